// Round 2
// baseline (350.362 us; speedup 1.0000x reference)
//
#include <hip/hip_runtime.h>
#include <math.h>

#define B_ 4
#define C_ 32
#define H_ 256
#define W_ 256
#define HW_ (H_ * W_)
#define K_ 9
#define TX 32
#define TY 8
#define HX 34              // TX + 2
#define HY 10              // TY + 2
#define HCH (HX * HY)      // 340 floats per channel halo
#define HTOT (HCH * C_)    // 10880 floats = 42.5 KB
#define EPS_ 1e-12f

__global__ __launch_bounds__(256, 3) void asfr_kernel(const float* __restrict__ fe,
                                                      const float* __restrict__ fu,
                                                      float* __restrict__ out) {
    __shared__ float smem[HTOT];
    const int t = threadIdx.x;
    const int bx = blockIdx.x & 7;          // W_/TX = 8
    const int by = (blockIdx.x >> 3) & 31;  // H_/TY = 32
    const int b  = blockIdx.x >> 8;
    const int w0 = bx * TX, h0 = by * TY;

    const int x = t & 31, y = t >> 5;
    const int pxoff = b * (C_ * HW_) + (h0 + y) * W_ + (w0 + x);

    // fe channel vector into registers (issued early, overlaps staging)
    float fereg[C_];
#pragma unroll
    for (int c = 0; c < C_; ++c) fereg[c] = fe[pxoff + c * HW_];

    // stage fu halo tile (all 32 channels) into LDS, zero-padded borders
    const float* fub = fu + b * (C_ * HW_);
#pragma unroll 6
    for (int j = 0; j < 42; ++j) {
        int i = t + j * 256;
        int c = i / HCH;
        int rem = i - c * HCH;
        int r = rem / HX;
        int col = rem - r * HX;
        int hh = h0 - 1 + r;
        int ww = w0 - 1 + col;
        float v = 0.f;
        if (((unsigned)hh < (unsigned)H_) && ((unsigned)ww < (unsigned)W_))
            v = fub[c * HW_ + hh * W_ + ww];
        smem[i] = v;
    }
    {   // tail: i = t + 42*256, valid for t < 128
        int i = t + 10752;
        if (i < HTOT) {
            int c = i / HCH;
            int rem = i - c * HCH;
            int r = rem / HX;
            int col = rem - r * HX;
            int hh = h0 - 1 + r;
            int ww = w0 - 1 + col;
            float v = 0.f;
            if (((unsigned)hh < (unsigned)H_) && ((unsigned)ww < (unsigned)W_))
                v = fub[c * HW_ + hh * W_ + ww];
            smem[i] = v;
        }
    }
    __syncthreads();

    const int hc = (y + 1) * HX + (x + 1);
    const int koff[K_] = {-HX - 1, -HX, -HX + 1, -1, 0, 1, HX - 1, HX, HX + 1};

    float dot[K_], psq[K_];
#pragma unroll
    for (int k = 0; k < K_; ++k) { dot[k] = 0.f; psq[k] = 0.f; }
    float fsq = 0.f;

    // Pass 1: per-k statistics, all from LDS + registers
#pragma unroll
    for (int c = 0; c < C_; ++c) {
        float f = fereg[c];
        fsq = fmaf(f, f, fsq);
        const int sb = c * HCH + hc;
#pragma unroll
        for (int k = 0; k < K_; ++k) {
            float p = smem[sb + koff[k]];
            dot[k] = fmaf(p, f, dot[k]);
            psq[k] = fmaf(p, p, psq[k]);
        }
    }

    float nf = fmaxf(sqrtf(fsq), EPS_);
    float cosv[K_], negd[K_];
#pragma unroll
    for (int k = 0; k < K_; ++k) {
        float np = fmaxf(sqrtf(psq[k]), EPS_);
        cosv[k] = __fdividef(dot[k], np * nf);
        // ||p - f||^2 = ||p||^2 - 2 p.f + ||f||^2
        float dsq = fmaxf(psq[k] - 2.f * dot[k] + fsq, 0.f);
        negd[k] = -sqrtf(dsq);
    }

    float m1 = cosv[0], m2 = negd[0];
#pragma unroll
    for (int k = 1; k < K_; ++k) { m1 = fmaxf(m1, cosv[k]); m2 = fmaxf(m2, negd[k]); }
    float s1 = 0.f, s2 = 0.f, e1[K_], e2[K_];
#pragma unroll
    for (int k = 0; k < K_; ++k) {
        e1[k] = __expf(cosv[k] - m1);
        e2[k] = __expf(negd[k] - m2);
        s1 += e1[k]; s2 += e2[k];
    }
    float r1 = __fdividef(0.5f, s1), r2 = __fdividef(0.5f, s2);
    float wt[K_];
#pragma unroll
    for (int k = 0; k < K_; ++k) wt[k] = fmaf(e1[k], r1, e2[k] * r2);

    // Pass 2: weighted gather from LDS + residual from registers
#pragma unroll
    for (int c = 0; c < C_; ++c) {
        const int sb = c * HCH + hc;
        float acc = fereg[c];
#pragma unroll
        for (int k = 0; k < K_; ++k) acc = fmaf(wt[k], smem[sb + koff[k]], acc);
        out[pxoff + c * HW_] = acc;
    }
}

extern "C" void kernel_launch(void* const* d_in, const int* in_sizes, int n_in,
                              void* d_out, int out_size, void* d_ws, size_t ws_size,
                              hipStream_t stream) {
    const float* fe = (const float*)d_in[0];
    const float* fu = (const float*)d_in[1];
    float* out = (float*)d_out;
    dim3 grid((W_ / TX) * (H_ / TY) * B_), block(256);  // 1024 blocks
    hipLaunchKernelGGL(asfr_kernel, grid, block, 0, stream, fe, fu, out);
}

// Round 3
// 135.177 us; speedup vs baseline: 2.5919x; 2.5919x over previous
//
#include <hip/hip_runtime.h>
#include <math.h>

#define B_ 4
#define C_ 32
#define H_ 256
#define W_ 256
#define HW_ (H_ * W_)
#define K_ 9
#define TX 32
#define TY 8
#define HX 34              // TX + 2
#define HY 10              // TY + 2
#define HCH (HX * HY)      // 340 floats per channel halo
#define HTOT (HCH * C_)    // 10880 floats = 42.5 KB
#define EPS_ 1e-12f

__global__ __launch_bounds__(256) void asfr_kernel(const float* __restrict__ fe,
                                                   const float* __restrict__ fu,
                                                   float* __restrict__ out) {
    __shared__ float smem[HTOT];
    const int t = threadIdx.x;
    const int bx = blockIdx.x & 7;          // W_/TX = 8
    const int by = (blockIdx.x >> 3) & 31;  // H_/TY = 32
    const int b  = blockIdx.x >> 8;
    const int w0 = bx * TX, h0 = by * TY;

    const int x = t & 31, y = t >> 5;
    const int pxoff = b * (C_ * HW_) + (h0 + y) * W_ + (w0 + x);

    // stage fu halo tile (all 32 channels) into LDS, zero-padded borders
    const float* fub = fu + b * (C_ * HW_);
#pragma unroll 6
    for (int j = 0; j < 42; ++j) {
        int i = t + j * 256;
        int c = i / HCH;
        int rem = i - c * HCH;
        int r = rem / HX;
        int col = rem - r * HX;
        int hh = h0 - 1 + r;
        int ww = w0 - 1 + col;
        float v = 0.f;
        if (((unsigned)hh < (unsigned)H_) && ((unsigned)ww < (unsigned)W_))
            v = fub[c * HW_ + hh * W_ + ww];
        smem[i] = v;
    }
    {   // tail: i = t + 42*256, valid for t < 128
        int i = t + 10752;
        if (i < HTOT) {
            int c = i / HCH;
            int rem = i - c * HCH;
            int r = rem / HX;
            int col = rem - r * HX;
            int hh = h0 - 1 + r;
            int ww = w0 - 1 + col;
            float v = 0.f;
            if (((unsigned)hh < (unsigned)H_) && ((unsigned)ww < (unsigned)W_))
                v = fub[c * HW_ + hh * W_ + ww];
            smem[i] = v;
        }
    }
    __syncthreads();

    const int hc = (y + 1) * HX + (x + 1);
    const int koff[K_] = {-HX - 1, -HX, -HX + 1, -1, 0, 1, HX - 1, HX, HX + 1};

    float dot[K_], psq[K_];
#pragma unroll
    for (int k = 0; k < K_; ++k) { dot[k] = 0.f; psq[k] = 0.f; }
    float fsq = 0.f;

    // Pass 1: per-k statistics; fu taps from LDS, fe streamed from global
#pragma unroll
    for (int c = 0; c < C_; ++c) {
        float f = fe[pxoff + c * HW_];
        fsq = fmaf(f, f, fsq);
        const int sb = c * HCH + hc;
#pragma unroll
        for (int k = 0; k < K_; ++k) {
            float p = smem[sb + koff[k]];
            dot[k] = fmaf(p, f, dot[k]);
            psq[k] = fmaf(p, p, psq[k]);
        }
    }

    float nf = fmaxf(sqrtf(fsq), EPS_);
    float cosv[K_], negd[K_];
#pragma unroll
    for (int k = 0; k < K_; ++k) {
        float np = fmaxf(sqrtf(psq[k]), EPS_);
        cosv[k] = __fdividef(dot[k], np * nf);
        // ||p - f||^2 = ||p||^2 - 2 p.f + ||f||^2
        float dsq = fmaxf(psq[k] - 2.f * dot[k] + fsq, 0.f);
        negd[k] = -sqrtf(dsq);
    }

    float m1 = cosv[0], m2 = negd[0];
#pragma unroll
    for (int k = 1; k < K_; ++k) { m1 = fmaxf(m1, cosv[k]); m2 = fmaxf(m2, negd[k]); }
    float s1 = 0.f, s2 = 0.f, e1[K_], e2[K_];
#pragma unroll
    for (int k = 0; k < K_; ++k) {
        e1[k] = __expf(cosv[k] - m1);
        e2[k] = __expf(negd[k] - m2);
        s1 += e1[k]; s2 += e2[k];
    }
    float r1 = __fdividef(0.5f, s1), r2 = __fdividef(0.5f, s2);
    float wt[K_];
#pragma unroll
    for (int k = 0; k < K_; ++k) wt[k] = fmaf(e1[k], r1, e2[k] * r2);

    // Pass 2: weighted gather from LDS + residual re-read from global (L2-warm)
#pragma unroll
    for (int c = 0; c < C_; ++c) {
        const int sb = c * HCH + hc;
        float acc = fe[pxoff + c * HW_];
#pragma unroll
        for (int k = 0; k < K_; ++k) acc = fmaf(wt[k], smem[sb + koff[k]], acc);
        out[pxoff + c * HW_] = acc;
    }
}

extern "C" void kernel_launch(void* const* d_in, const int* in_sizes, int n_in,
                              void* d_out, int out_size, void* d_ws, size_t ws_size,
                              hipStream_t stream) {
    const float* fe = (const float*)d_in[0];
    const float* fu = (const float*)d_in[1];
    float* out = (float*)d_out;
    dim3 grid((W_ / TX) * (H_ / TY) * B_), block(256);  // 1024 blocks
    hipLaunchKernelGGL(asfr_kernel, grid, block, 0, stream, fe, fu, out);
}

// Round 4
// 41.904 us; speedup vs baseline: 8.3611x; 3.2259x over previous
//
#include <hip/hip_runtime.h>
#include <math.h>

#define B_ 4
#define C_ 32
#define H_ 256
#define W_ 256
#define HW_ (H_ * W_)
#define K_ 9
#define TX 32
#define TY 4
#define HX 34              // TX + 2
#define HY 6               // TY + 2
#define HCH (HX * HY)      // 204 floats per channel halo
#define HTOT (HCH * C_)    // 6528 floats = 25.5 KB
#define EPS_ 1e-12f

// 256 threads = 4 waves. Each wave owns 32 pixels (one row of the 32x4 tile);
// lane&31 = x, lane>>5 = channel-half. 2 threads/pixel doubles wave-parallelism
// (8192 waves total -> up to 32/CU). launch_bounds(256,6): cap VGPR ~85, no
// 32-float register caches live across the softmax (R2 lesson).
__global__ __launch_bounds__(256, 6) void asfr_kernel(const float* __restrict__ fe,
                                                      const float* __restrict__ fu,
                                                      float* __restrict__ out) {
    __shared__ float smem[HTOT];
    const int t = threadIdx.x;
    const int bx = blockIdx.x & 7;           // W_/TX = 8
    const int by = (blockIdx.x >> 3) & 63;   // H_/TY = 64
    const int b  = blockIdx.x >> 9;
    const int w0 = bx * TX, h0 = by * TY;

    // stage fu halo tile (all 32 channels) into LDS, zero-padded borders
    const float* fub = fu + b * (C_ * HW_);
#pragma unroll 5
    for (int j = 0; j < 25; ++j) {
        int i = t + j * 256;
        int c = i / HCH;
        int rem = i - c * HCH;
        int r = rem / HX;
        int col = rem - r * HX;
        int hh = h0 - 1 + r;
        int ww = w0 - 1 + col;
        float v = 0.f;
        if (((unsigned)hh < (unsigned)H_) && ((unsigned)ww < (unsigned)W_))
            v = fub[c * HW_ + hh * W_ + ww];
        smem[i] = v;
    }
    {   // tail: i = t + 25*256, valid for t < 128
        int i = t + 6400;
        if (i < HTOT) {
            int c = i / HCH;
            int rem = i - c * HCH;
            int r = rem / HX;
            int col = rem - r * HX;
            int hh = h0 - 1 + r;
            int ww = w0 - 1 + col;
            float v = 0.f;
            if (((unsigned)hh < (unsigned)H_) && ((unsigned)ww < (unsigned)W_))
                v = fub[c * HW_ + hh * W_ + ww];
            smem[i] = v;
        }
    }
    __syncthreads();

    const int x = t & 31;            // pixel x within tile
    const int y = t >> 6;            // pixel y within tile (= wave id)
    const int half = (t >> 5) & 1;   // channel half: 0 -> c 0..15, 1 -> c 16..31
    const int c0 = half << 4;

    const int pxoff = b * (C_ * HW_) + (h0 + y) * W_ + (w0 + x);
    const int hc = (y + 1) * HX + (x + 1);
    const int koff[K_] = {-HX - 1, -HX, -HX + 1, -1, 0, 1, HX - 1, HX, HX + 1};

    float dot[K_], psq[K_];
#pragma unroll
    for (int k = 0; k < K_; ++k) { dot[k] = 0.f; psq[k] = 0.f; }
    float fsq = 0.f;

    // Pass 1: per-k statistics over this half's 16 channels
#pragma unroll 4
    for (int cc = 0; cc < 16; ++cc) {
        const int c = c0 + cc;
        float f = fe[pxoff + c * HW_];
        fsq = fmaf(f, f, fsq);
        const int sb = c * HCH + hc;
#pragma unroll
        for (int k = 0; k < K_; ++k) {
            float p = smem[sb + koff[k]];
            dot[k] = fmaf(p, f, dot[k]);
            psq[k] = fmaf(p, p, psq[k]);
        }
    }

    // combine halves: lane l and l^32 hold the two channel-halves of one pixel
#pragma unroll
    for (int k = 0; k < K_; ++k) {
        dot[k] += __shfl_xor(dot[k], 32);
        psq[k] += __shfl_xor(psq[k], 32);
    }
    fsq += __shfl_xor(fsq, 32);

    float nf = fmaxf(sqrtf(fsq), EPS_);
    float cosv[K_], negd[K_];
#pragma unroll
    for (int k = 0; k < K_; ++k) {
        float np = fmaxf(sqrtf(psq[k]), EPS_);
        cosv[k] = __fdividef(dot[k], np * nf);
        float dsq = fmaxf(psq[k] - 2.f * dot[k] + fsq, 0.f);   // ||p-f||^2
        negd[k] = -sqrtf(dsq);
    }

    float m1 = cosv[0], m2 = negd[0];
#pragma unroll
    for (int k = 1; k < K_; ++k) { m1 = fmaxf(m1, cosv[k]); m2 = fmaxf(m2, negd[k]); }
    float s1 = 0.f, s2 = 0.f, e1[K_], e2[K_];
#pragma unroll
    for (int k = 0; k < K_; ++k) {
        e1[k] = __expf(cosv[k] - m1);
        e2[k] = __expf(negd[k] - m2);
        s1 += e1[k]; s2 += e2[k];
    }
    float r1 = __fdividef(0.5f, s1), r2 = __fdividef(0.5f, s2);
    float wt[K_];
#pragma unroll
    for (int k = 0; k < K_; ++k) wt[k] = fmaf(e1[k], r1, e2[k] * r2);

    // Pass 2: weighted gather for this half's 16 channels
#pragma unroll 4
    for (int cc = 0; cc < 16; ++cc) {
        const int c = c0 + cc;
        const int sb = c * HCH + hc;
        float acc = fe[pxoff + c * HW_];
#pragma unroll
        for (int k = 0; k < K_; ++k) acc = fmaf(wt[k], smem[sb + koff[k]], acc);
        out[pxoff + c * HW_] = acc;
    }
}

extern "C" void kernel_launch(void* const* d_in, const int* in_sizes, int n_in,
                              void* d_out, int out_size, void* d_ws, size_t ws_size,
                              hipStream_t stream) {
    const float* fe = (const float*)d_in[0];
    const float* fu = (const float*)d_in[1];
    float* out = (float*)d_out;
    dim3 grid((W_ / TX) * (H_ / TY) * B_), block(256);  // 2048 blocks
    hipLaunchKernelGGL(asfr_kernel, grid, block, 0, stream, fe, fu, out);
}